// Round 6
// baseline (1936.164 us; speedup 1.0000x reference)
//
#include <hip/hip_runtime.h>
#include <hip/hip_cooperative_groups.h>
#include <hip/hip_bf16.h>
#include <math.h>

namespace cg = cooperative_groups;

// Shapes
#define N_TRAIN 4096
#define N_FEAT  64
#define N_HID   256
#define ENC     256
#define N_ANTES 2048
#define ATT_H   256
#define MAX_LEN 16

typedef unsigned int u32;

__device__ __forceinline__ float fsig(float x)  { return 1.f / (1.f + __expf(-x)); }
__device__ __forceinline__ float ftanh(float x) { return 2.f / (1.f + __expf(-2.f * x)) - 1.f; }

// ---------------------------------------------------------------------------
// Tiled GEMM: C[m,n] = act(bias[n] + sum_k A[m,k] * B[n,k]); 64x64x16 tiles.
// ---------------------------------------------------------------------------
template <bool RELU>
__global__ __launch_bounds__(256) void gemm_abT(
    const float* __restrict__ A, const float* __restrict__ B,
    const float* __restrict__ bias, float* __restrict__ C,
    int M, int N, int K, int lda, int ldb, int ldc)
{
    __shared__ __align__(16) float As[16][68];
    __shared__ __align__(16) float Bs[16][68];
    const int tid = threadIdx.x;
    const int m0 = blockIdx.x * 64, n0 = blockIdx.y * 64;
    const int tx = tid & 15, ty = tid >> 4;
    const int kl = tid & 15, rl = tid >> 4;
    float acc[4][4] = {};

    for (int k0 = 0; k0 < K; k0 += 16) {
        #pragma unroll
        for (int pp = 0; pp < 4; ++pp) {
            int r = rl + pp * 16;
            As[kl][r] = A[(size_t)(m0 + r) * lda + k0 + kl];
            Bs[kl][r] = B[(size_t)(n0 + r) * ldb + k0 + kl];
        }
        __syncthreads();
        #pragma unroll
        for (int k = 0; k < 16; ++k) {
            float4 av = *(const float4*)&As[k][ty * 4];
            float4 bv = *(const float4*)&Bs[k][tx * 4];
            float a4[4] = {av.x, av.y, av.z, av.w};
            float b4[4] = {bv.x, bv.y, bv.z, bv.w};
            #pragma unroll
            for (int i = 0; i < 4; ++i)
                #pragma unroll
                for (int j = 0; j < 4; ++j)
                    acc[i][j] = fmaf(a4[i], b4[j], acc[i][j]);
        }
        __syncthreads();
    }
    #pragma unroll
    for (int i = 0; i < 4; ++i) {
        int m = m0 + ty * 4 + i;
        #pragma unroll
        for (int j = 0; j < 4; ++j) {
            int n = n0 + tx * 4 + j;
            float v = acc[i][j] + bias[n];
            if (RELU) v = fmaxf(v, 0.f);
            C[(size_t)m * ldc + n] = v;
        }
    }
}

// ---------------------------------------------------------------------------
// Split-K GEMM, partials to plain buffers. Grid (M/64,N/64,4). float4 staging.
// ---------------------------------------------------------------------------
#define KSPLIT 4
__global__ __launch_bounds__(256) void gemm_ab_splitk(
    const float* __restrict__ A, const float* __restrict__ B,
    float* __restrict__ pA, float* __restrict__ pB,
    int M, int N, int K, int lda, int ldb, int ldc)
{
    __shared__ __align__(16) float As[16][68];
    __shared__ __align__(16) float Bs[16][68];
    const int tid = threadIdx.x;
    const int m0 = blockIdx.x * 64, n0 = blockIdx.y * 64;
    const int kchunk = K / KSPLIT;
    const int kbeg = blockIdx.z * kchunk, kend = kbeg + kchunk;
    const int tx = tid & 15, ty = tid >> 4;
    const int arow = tid & 63, akq = tid >> 6;   // A: 64 rows x 4 k-quads
    const int bnq = tid & 15, bkk = tid >> 4;    // B: 16 n-quads x 16 k
    float acc[4][4] = {};

    for (int k0 = kbeg; k0 < kend; k0 += 16) {
        float4 av4 = *(const float4*)&A[(size_t)(m0 + arow) * lda + k0 + akq * 4];
        float4 bv4 = *(const float4*)&B[(size_t)(k0 + bkk) * ldb + n0 + bnq * 4];
        As[akq * 4 + 0][arow] = av4.x;
        As[akq * 4 + 1][arow] = av4.y;
        As[akq * 4 + 2][arow] = av4.z;
        As[akq * 4 + 3][arow] = av4.w;
        *(float4*)&Bs[bkk][bnq * 4] = bv4;
        __syncthreads();
        #pragma unroll
        for (int k = 0; k < 16; ++k) {
            float4 av = *(const float4*)&As[k][ty * 4];
            float4 bv = *(const float4*)&Bs[k][tx * 4];
            float a4[4] = {av.x, av.y, av.z, av.w};
            float b4[4] = {bv.x, bv.y, bv.z, bv.w};
            #pragma unroll
            for (int i = 0; i < 4; ++i)
                #pragma unroll
                for (int j = 0; j < 4; ++j)
                    acc[i][j] = fmaf(a4[i], b4[j], acc[i][j]);
        }
        __syncthreads();
    }
    float* Cp = (blockIdx.z < 2) ? (pA + (size_t)blockIdx.z * (ATT_H * N_ANTES))
                                 : (pB + (size_t)(blockIdx.z - 2) * (ATT_H * N_ANTES));
    #pragma unroll
    for (int i = 0; i < 4; ++i)
        #pragma unroll
        for (int j = 0; j < 4; ++j)
            Cp[(size_t)(m0 + ty * 4 + i) * ldc + n0 + tx * 4 + j] = acc[i][j];
}

// ---------------------------------------------------------------------------
// Sum 4 split-K partials [j][p] and write TRANSPOSED pre[p][j] (p-major so the
// persistent loop's per-block score reads are coalesced). 32x32 LDS tiles.
// Grid (256/32, 2048/32) = (8, 64), 256 threads.
// ---------------------------------------------------------------------------
__global__ __launch_bounds__(256) void k_reduceT(
    const float* __restrict__ pA, const float* __restrict__ pB,
    float* __restrict__ pre)
{
    __shared__ float tile[32][33];
    const int tid = threadIdx.x;
    const int lj = tid >> 5, lp = tid & 31;    // 8 x 32
    const int SZ = ATT_H * N_ANTES;
    #pragma unroll
    for (int q = 0; q < 4; ++q) {
        int j = blockIdx.x * 32 + lj + q * 8;
        int p = blockIdx.y * 32 + lp;
        size_t off = (size_t)j * N_ANTES + p;
        tile[lj + q * 8][lp] = (pA[off] + pA[off + SZ]) + (pB[off] + pB[off + SZ]);
    }
    __syncthreads();
    #pragma unroll
    for (int q = 0; q < 4; ++q) {
        int p = blockIdx.y * 32 + lj + q * 8;
        int j = blockIdx.x * 32 + lp;
        pre[(size_t)p * 256 + j] = tile[lp][lj + q * 8];
    }
}

// ---------------------------------------------------------------------------
// rowsum[j] = sum_k w_ih[j, k]
// ---------------------------------------------------------------------------
__global__ __launch_bounds__(256) void k_rowsum(const float* __restrict__ w_ih,
                                                float* __restrict__ rowsum)
{
    __shared__ float red[256];
    const int j = blockIdx.x, tid = threadIdx.x;
    float s = 0.f;
    for (int i = tid; i < N_ANTES; i += 256) s += w_ih[(size_t)j * N_ANTES + i];
    red[tid] = s; __syncthreads();
    for (int off = 128; off > 0; off >>= 1) {
        if (tid < off) red[tid] += red[tid + off];
        __syncthreads();
    }
    if (tid == 0) rowsum[j] = red[0];
}

// ---------------------------------------------------------------------------
// wpkT[k*1024 + j] = w_hh[j*256 + k]
// ---------------------------------------------------------------------------
__global__ __launch_bounds__(256) void k_packT(const float* __restrict__ w_hh,
                                               float* __restrict__ wpkT)
{
    int gid = blockIdx.x * 256 + threadIdx.x;
    int j = gid >> 8;
    int k = gid & 255;
    wpkT[(size_t)k * 1024 + j] = w_hh[gid];
}

// ---------------------------------------------------------------------------
// WbT[k*256 + j] = att_w1[j*(N_TRAIN+ENC) + N_TRAIN + k]
// ---------------------------------------------------------------------------
__global__ __launch_bounds__(256) void k_wbT(const float* __restrict__ att_w1,
                                             float* __restrict__ WbT)
{
    int gid = blockIdx.x * 256 + threadIdx.x;
    int j = gid >> 8, k = gid & 255;
    WbT[(size_t)k * 256 + j] = att_w1[(size_t)j * (N_TRAIN + ENC) + N_TRAIN + k];
}

// ---------------------------------------------------------------------------
// Persistent cooperative kernel: all 16 LSTM+attention steps in one launch.
// Grid 256 x 1024 threads, 1 block/CU (93 KB LDS). Block owns 16 LSTM rows:
// h in LDS, c in registers, across all steps. 2 grid syncs per step.
// ---------------------------------------------------------------------------
#define LROWS 16
#define HSTR 20
__global__ __launch_bounds__(1024, 4) void k_loop(
    const float* __restrict__ h0, const float* __restrict__ wpkT,
    const float* __restrict__ rowsum, const float* __restrict__ b_ih,
    const float* __restrict__ b_hh, const float* __restrict__ S,
    const float* __restrict__ pre, const float* __restrict__ WbT,
    const float* __restrict__ att_b1, const float* __restrict__ att_w2,
    const float* __restrict__ att_b2, float* __restrict__ e_acc,
    float* __restrict__ scores, float* __restrict__ out)
{
    cg::grid_group grid = cg::this_grid();
    __shared__ __align__(16) float h_lds[256 * HSTR];   // [k][r], 20 KB
    __shared__ float z_lds[LROWS * 1024];               // [r][j], 64 KB
    __shared__ float red[1024];
    __shared__ float a_lds[LROWS];
    __shared__ float e_lds[256];
    __shared__ float u_lds[256];
    __shared__ float w2s[256];
    int* ridx = (int*)z_lds;                            // reuse (phase 5)

    const int tid = threadIdx.x;
    const int bid = blockIdx.x;
    const int n0 = bid * LROWS;
    const int jj = tid & 255, rq = tid >> 8;

    float creg[4] = {0.f, 0.f, 0.f, 0.f};               // persistent c

    if (tid < 256) {
        #pragma unroll
        for (int r = 0; r < LROWS; ++r)
            h_lds[tid * HSTR + r] = h0[(size_t)(n0 + r) * 256 + tid];
        w2s[tid] = att_w2[tid];
    }
    const float rs = rowsum[tid];
    const float bs = b_ih[tid] + b_hh[tid];
    const float ab2 = att_b2[0];
    int idx_prev = 0;
    __syncthreads();

    for (int t = 0; t < MAX_LEN; ++t) {
        // ---- phase 1: x column a[r] (x is rank-1: S[:,idx] or ones) ----
        if (tid < LROWS) {
            float a = 1.0f;
            if (t > 0) a = S[(size_t)(n0 + tid) * N_ANTES + idx_prev];
            a_lds[tid] = a;
        }
        __syncthreads();

        // ---- phase 2: z[j] = a*rowsum + bias + dot(h_row, w_hh[j]) ----
        float acc[LROWS];
        #pragma unroll
        for (int r = 0; r < LROWS; ++r) acc[r] = fmaf(a_lds[r], rs, bs);
        float wbuf[4];
        #pragma unroll
        for (int i = 0; i < 4; ++i) wbuf[i] = wpkT[(size_t)i * 1024 + tid];
        for (int k4 = 0; k4 < 256; k4 += 4) {
            #pragma unroll
            for (int u = 0; u < 4; ++u) {
                float w = wbuf[u];
                wbuf[u] = wpkT[(size_t)(k4 + 4 + u) * 1024 + tid];  // pad rows
                const float4* hrow = (const float4*)&h_lds[(k4 + u) * HSTR];
                float4 h0v = hrow[0], h1v = hrow[1], h2v = hrow[2], h3v = hrow[3];
                float hk[LROWS] = {h0v.x, h0v.y, h0v.z, h0v.w,
                                   h1v.x, h1v.y, h1v.z, h1v.w,
                                   h2v.x, h2v.y, h2v.z, h2v.w,
                                   h3v.x, h3v.y, h3v.z, h3v.w};
                #pragma unroll
                for (int r = 0; r < LROWS; ++r)
                    acc[r] = fmaf(w, hk[r], acc[r]);
            }
        }

        // ---- phase 3: gate update, h/c in place, e partial ----
        #pragma unroll
        for (int r = 0; r < LROWS; ++r) z_lds[r * 1024 + tid] = acc[r];
        __syncthreads();
        float esum = 0.f;
        float hnew[4];
        #pragma unroll
        for (int i = 0; i < 4; ++i) {
            int r = rq * 4 + i;
            float zi = z_lds[r * 1024 + jj];
            float zf = z_lds[r * 1024 + 256 + jj];
            float zg = z_lds[r * 1024 + 512 + jj];
            float zo = z_lds[r * 1024 + 768 + jj];
            float cn = fsig(zf) * creg[i] + fsig(zi) * ftanh(zg);
            float hn = fsig(zo) * ftanh(cn);
            creg[i] = cn;
            hnew[i] = hn;
            esum += hn;
        }
        #pragma unroll
        for (int i = 0; i < 4; ++i)
            h_lds[jj * HSTR + rq * 4 + i] = hnew[i];
        red[tid] = esum;
        __syncthreads();
        if (tid < 256) {
            float e = (red[tid] + red[tid + 256]) + (red[tid + 512] + red[tid + 768]);
            atomicAdd(&e_acc[t * 256 + tid], e);
        }
        grid.sync();                        // e_acc complete

        // ---- phase 4: u[j], then this block's 8 score columns ----
        if (tid < 256)
            e_lds[tid] = __hip_atomic_load(&e_acc[t * 256 + tid], __ATOMIC_RELAXED,
                                           __HIP_MEMORY_SCOPE_AGENT) * (1.f / (float)N_TRAIN);
        __syncthreads();
        {
            float ua = 0.f;
            for (int k = rq * 64; k < rq * 64 + 64; ++k)
                ua = fmaf(e_lds[k], WbT[(size_t)k * 256 + jj], ua);
            red[tid] = ua;
            __syncthreads();
            if (tid < 256)
                u_lds[tid] = att_b1[tid] +
                    ((red[tid] + red[tid + 256]) + (red[tid + 512] + red[tid + 768]));
        }
        __syncthreads();
        {
            int col = tid >> 7, i = tid & 127;
            int p = bid * 8 + col;
            float v1 = pre[(size_t)p * 256 + i] + u_lds[i];
            float v2 = pre[(size_t)p * 256 + i + 128] + u_lds[i + 128];
            float sc = fmaf(fmaxf(v1, 0.f), w2s[i],
                            fmaxf(v2, 0.f) * w2s[i + 128]);
            red[tid] = sc;
            __syncthreads();
            for (int off = 64; off > 0; off >>= 1) {
                if (i < off) red[col * 128 + i] += red[col * 128 + i + off];
                __syncthreads();
            }
            if (tid < 8)
                __hip_atomic_store(&scores[bid * 8 + tid], red[tid * 128] + ab2,
                                   __ATOMIC_RELAXED, __HIP_MEMORY_SCOPE_AGENT);
        }
        grid.sync();                        // all 2048 scores complete

        // ---- phase 5: redundant softmax/argmax per block (bitwise equal) ----
        float sv0 = __hip_atomic_load(&scores[tid * 2], __ATOMIC_RELAXED,
                                      __HIP_MEMORY_SCOPE_AGENT);
        float sv1 = __hip_atomic_load(&scores[tid * 2 + 1], __ATOMIC_RELAXED,
                                      __HIP_MEMORY_SCOPE_AGENT);
        __syncthreads();                     // z_lds (ridx) safe to reuse
        float lmax = (sv1 > sv0) ? sv1 : sv0;
        int   lidx = (sv1 > sv0) ? tid * 2 + 1 : tid * 2;
        red[tid] = lmax; ridx[tid] = lidx;
        __syncthreads();
        for (int off = 512; off > 0; off >>= 1) {
            if (tid < off) {
                float ov = red[tid + off]; int oi = ridx[tid + off];
                if (ov > red[tid] || (ov == red[tid] && oi < ridx[tid])) {
                    red[tid] = ov; ridx[tid] = oi;
                }
            }
            __syncthreads();
        }
        const float gmax = red[0];
        const int gidx = ridx[0];
        __syncthreads();
        red[tid] = __expf(sv0 - gmax) + __expf(sv1 - gmax);
        __syncthreads();
        for (int off = 512; off > 0; off >>= 1) {
            if (tid < off) red[tid] += red[tid + off];
            __syncthreads();
        }
        const float lse = gmax + logf(red[0]);
        if (bid == 0) {
            out[(size_t)t * N_ANTES + tid * 2]     = sv0 - lse;
            out[(size_t)t * N_ANTES + tid * 2 + 1] = sv1 - lse;
        }
        idx_prev = gidx;
        __syncthreads();
    }
}

// ---------------------------------------------------------------------------
extern "C" void kernel_launch(void* const* d_in, const int* in_sizes, int n_in,
                              void* d_out, int out_size, void* d_ws, size_t ws_size,
                              hipStream_t stream)
{
    (void)in_sizes; (void)n_in; (void)out_size; (void)ws_size;
    const float* context = (const float*)d_in[0];
    const float* S       = (const float*)d_in[1];
    const float* enc_w1  = (const float*)d_in[2];
    const float* enc_b1  = (const float*)d_in[3];
    const float* enc_w2  = (const float*)d_in[4];
    const float* enc_b2  = (const float*)d_in[5];
    const float* w_ih    = (const float*)d_in[6];
    const float* w_hh    = (const float*)d_in[7];
    const float* b_ih    = (const float*)d_in[8];
    const float* b_hh    = (const float*)d_in[9];
    const float* att_w1  = (const float*)d_in[10];
    const float* att_b1  = (const float*)d_in[11];
    const float* att_w2  = (const float*)d_in[12];
    const float* att_b2  = (const float*)d_in[13];
    float* out = (float*)d_out;
    float* ws  = (float*)d_ws;

    // ws layout (float offsets)
    float* h0     = ws;                        // 1,048,576
    float* pAbuf  = ws + 1048576;              // 1,048,576 (hid1 aliases slice 0)
    float* pBbuf  = ws + 2097152;              // 1,048,576
    float* pre    = ws + 3145728;              // 524,288  (p-major: [p][j])
    float* wpkT   = ws + 3670016;              // 262,144 + 4,096 pad
    float* rowsum = ws + 3936256;              // 1,024
    float* e_acc  = ws + 3937280;              // 4,096
    float* scores = ws + 3941376;              // 2,048
    float* WbT    = ws + 3943424;              // 65,536

    hipMemsetAsync(e_acc, 0, (size_t)MAX_LEN * ENC * sizeof(float), stream);

    k_rowsum<<<1024, 256, 0, stream>>>(w_ih, rowsum);
    k_packT<<<1024, 256, 0, stream>>>(w_hh, wpkT);
    k_wbT<<<256, 256, 0, stream>>>(att_w1, WbT);

    // encoder: hid1 = relu(context @ enc_w1.T + b1); h0 = hid1 @ enc_w2.T + b2
    float* hid1 = pAbuf;
    dim3 g1(N_TRAIN / 64, N_HID / 64);
    gemm_abT<true><<<g1, 256, 0, stream>>>(context, enc_w1, enc_b1, hid1,
                                           N_TRAIN, N_HID, N_FEAT, N_FEAT, N_FEAT, N_HID);
    dim3 g2(N_TRAIN / 64, ENC / 64);
    gemm_abT<false><<<g2, 256, 0, stream>>>(hid1, enc_w2, enc_b2, h0,
                                            N_TRAIN, ENC, N_HID, N_HID, N_HID, ENC);
    // preT partials (pAbuf reused after gemm #2 consumed hid1; stream order)
    dim3 g3(ATT_H / 64, N_ANTES / 64, KSPLIT);
    gemm_ab_splitk<<<g3, 256, 0, stream>>>(att_w1, S, pAbuf, pBbuf,
                                           ATT_H, N_ANTES, N_TRAIN,
                                           N_TRAIN + ENC, N_ANTES, N_ANTES);
    k_reduceT<<<dim3(ATT_H / 32, N_ANTES / 32), 256, 0, stream>>>(pAbuf, pBbuf, pre);

    // persistent 16-step loop (cooperative: grid-wide sync)
    void* kargs[] = {
        (void*)&h0, (void*)&wpkT, (void*)&rowsum, (void*)&b_ih, (void*)&b_hh,
        (void*)&S, (void*)&pre, (void*)&WbT, (void*)&att_b1, (void*)&att_w2,
        (void*)&att_b2, (void*)&e_acc, (void*)&scores, (void*)&out
    };
    hipLaunchCooperativeKernel((void*)k_loop, dim3(256), dim3(1024),
                               kargs, 0, stream);
}

// Round 7
// 1204.993 us; speedup vs baseline: 1.6068x; 1.6068x over previous
//
#include <hip/hip_runtime.h>
#include <hip/hip_bf16.h>
#include <math.h>

// Shapes
#define N_TRAIN 4096
#define N_FEAT  64
#define N_HID   256
#define ENC     256
#define N_ANTES 2048
#define ATT_H   256
#define MAX_LEN 16

typedef unsigned int u32;

__device__ __forceinline__ float fsig(float x)  { return 1.f / (1.f + __expf(-x)); }
__device__ __forceinline__ float ftanh(float x) { return 2.f / (1.f + __expf(-2.f * x)) - 1.f; }

// ---------------------------------------------------------------------------
// Tiled GEMM: C[m,n] = act(bias[n] + sum_k A[m,k] * B[n,k]); 64x64x16 tiles.
// ---------------------------------------------------------------------------
template <bool RELU>
__global__ __launch_bounds__(256) void gemm_abT(
    const float* __restrict__ A, const float* __restrict__ B,
    const float* __restrict__ bias, float* __restrict__ C,
    int M, int N, int K, int lda, int ldb, int ldc)
{
    __shared__ __align__(16) float As[16][68];
    __shared__ __align__(16) float Bs[16][68];
    const int tid = threadIdx.x;
    const int m0 = blockIdx.x * 64, n0 = blockIdx.y * 64;
    const int tx = tid & 15, ty = tid >> 4;
    const int kl = tid & 15, rl = tid >> 4;
    float acc[4][4] = {};

    for (int k0 = 0; k0 < K; k0 += 16) {
        #pragma unroll
        for (int pp = 0; pp < 4; ++pp) {
            int r = rl + pp * 16;
            As[kl][r] = A[(size_t)(m0 + r) * lda + k0 + kl];
            Bs[kl][r] = B[(size_t)(n0 + r) * ldb + k0 + kl];
        }
        __syncthreads();
        #pragma unroll
        for (int k = 0; k < 16; ++k) {
            float4 av = *(const float4*)&As[k][ty * 4];
            float4 bv = *(const float4*)&Bs[k][tx * 4];
            float a4[4] = {av.x, av.y, av.z, av.w};
            float b4[4] = {bv.x, bv.y, bv.z, bv.w};
            #pragma unroll
            for (int i = 0; i < 4; ++i)
                #pragma unroll
                for (int j = 0; j < 4; ++j)
                    acc[i][j] = fmaf(a4[i], b4[j], acc[i][j]);
        }
        __syncthreads();
    }
    #pragma unroll
    for (int i = 0; i < 4; ++i) {
        int m = m0 + ty * 4 + i;
        #pragma unroll
        for (int j = 0; j < 4; ++j) {
            int n = n0 + tx * 4 + j;
            float v = acc[i][j] + bias[n];
            if (RELU) v = fmaxf(v, 0.f);
            C[(size_t)m * ldc + n] = v;
        }
    }
}

// ---------------------------------------------------------------------------
// Split-K GEMM, KSPLIT=8, atomicAdd epilogue into zeroed C.
// Grid (M/64, N/64, 8) = 1024 blocks (4 blocks/CU). float4 staging with
// register double-buffer: next iter's global loads overlap this iter's FMAs.
// ---------------------------------------------------------------------------
#define KSPLIT 8
__global__ __launch_bounds__(256) void gemm_ab_splitk(
    const float* __restrict__ A, const float* __restrict__ B,
    float* __restrict__ C, int M, int N, int K, int lda, int ldb, int ldc)
{
    __shared__ __align__(16) float As[16][68];
    __shared__ __align__(16) float Bs[16][68];
    const int tid = threadIdx.x;
    const int m0 = blockIdx.x * 64, n0 = blockIdx.y * 64;
    const int kchunk = K / KSPLIT;
    const int kbeg = blockIdx.z * kchunk, kend = kbeg + kchunk;
    const int tx = tid & 15, ty = tid >> 4;
    const int arow = tid & 63, akq = tid >> 6;   // A: 64 rows x 4 k-quads
    const int bnq = tid & 15, bkk = tid >> 4;    // B: 16 n-quads x 16 k
    float acc[4][4] = {};

    float4 avn = *(const float4*)&A[(size_t)(m0 + arow) * lda + kbeg + akq * 4];
    float4 bvn = *(const float4*)&B[(size_t)(kbeg + bkk) * ldb + n0 + bnq * 4];

    for (int k0 = kbeg; k0 < kend; k0 += 16) {
        float4 av = avn, bv = bvn;
        if (k0 + 16 < kend) {
            avn = *(const float4*)&A[(size_t)(m0 + arow) * lda + k0 + 16 + akq * 4];
            bvn = *(const float4*)&B[(size_t)(k0 + 16 + bkk) * ldb + n0 + bnq * 4];
        }
        __syncthreads();             // prev iter's compute done -> LDS free
        As[akq * 4 + 0][arow] = av.x;
        As[akq * 4 + 1][arow] = av.y;
        As[akq * 4 + 2][arow] = av.z;
        As[akq * 4 + 3][arow] = av.w;
        *(float4*)&Bs[bkk][bnq * 4] = bv;
        __syncthreads();
        #pragma unroll
        for (int k = 0; k < 16; ++k) {
            float4 a4v = *(const float4*)&As[k][ty * 4];
            float4 b4v = *(const float4*)&Bs[k][tx * 4];
            float a4[4] = {a4v.x, a4v.y, a4v.z, a4v.w};
            float b4[4] = {b4v.x, b4v.y, b4v.z, b4v.w};
            #pragma unroll
            for (int i = 0; i < 4; ++i)
                #pragma unroll
                for (int j = 0; j < 4; ++j)
                    acc[i][j] = fmaf(a4[i], b4[j], acc[i][j]);
        }
    }
    #pragma unroll
    for (int i = 0; i < 4; ++i)
        #pragma unroll
        for (int j = 0; j < 4; ++j)
            atomicAdd(&C[(size_t)(m0 + ty * 4 + i) * ldc + n0 + tx * 4 + j],
                      acc[i][j]);
}

// ---------------------------------------------------------------------------
// rowsum[j] = sum_k w_ih[j, k]
// ---------------------------------------------------------------------------
__global__ __launch_bounds__(256) void k_rowsum(const float* __restrict__ w_ih,
                                                float* __restrict__ rowsum)
{
    __shared__ float red[256];
    const int j = blockIdx.x, tid = threadIdx.x;
    float s = 0.f;
    for (int i = tid; i < N_ANTES; i += 256) s += w_ih[(size_t)j * N_ANTES + i];
    red[tid] = s; __syncthreads();
    for (int off = 128; off > 0; off >>= 1) {
        if (tid < off) red[tid] += red[tid + off];
        __syncthreads();
    }
    if (tid == 0) rowsum[j] = red[0];
}

// ---------------------------------------------------------------------------
// wpkT[k*1024 + j] = w_hh[j*256 + k]   (k-major: coalesced per-k loads)
// ---------------------------------------------------------------------------
__global__ __launch_bounds__(256) void k_packT(const float* __restrict__ w_hh,
                                               float* __restrict__ wpkT)
{
    int gid = blockIdx.x * 256 + threadIdx.x;
    int j = gid >> 8;
    int k = gid & 255;
    wpkT[(size_t)k * 1024 + j] = w_hh[gid];
}

// ---------------------------------------------------------------------------
// WbT[k*256 + j] = att_w1[j*(N_TRAIN+ENC) + N_TRAIN + k]
// ---------------------------------------------------------------------------
__global__ __launch_bounds__(256) void k_wbT(const float* __restrict__ att_w1,
                                             float* __restrict__ WbT)
{
    int gid = blockIdx.x * 256 + threadIdx.x;
    int j = gid >> 8, k = gid & 255;
    WbT[(size_t)k * 256 + j] = att_w1[(size_t)j * (N_TRAIN + ENC) + N_TRAIN + k];
}

// ---------------------------------------------------------------------------
// LSTM step: 1024 threads/block, grid 256 (16 waves/CU). Thread tid owns
// gate-row j = tid. Per k: 1 coalesced wpkT load (8-deep register prefetch,
// no barrier in K-loop) + broadcast ds_read_b128 of h tile + 16 FMAs.
// ---------------------------------------------------------------------------
#define LROWS 16
#define HSTR 20
__global__ __launch_bounds__(1024, 4) void k_lstm(
    float* __restrict__ h, float* __restrict__ c,
    const float* __restrict__ wpkT, const float* __restrict__ rowsum,
    const float* __restrict__ b_ih, const float* __restrict__ b_hh,
    const float* __restrict__ S, const int* __restrict__ idx_buf, int t,
    float* __restrict__ e_accum_t)
{
    __shared__ __align__(16) float h_lds[256 * HSTR];   // [k][r], 20 KB
    __shared__ float z_lds[LROWS * 1024];               // [r][j], 64 KB
    __shared__ float red[1024];
    __shared__ float a_lds[LROWS];
    const int tid = threadIdx.x;
    const int n0 = blockIdx.x * LROWS;
    const int jj = tid & 255, rq = tid >> 8;

    if (tid < LROWS) {
        float a = 1.0f;
        if (t > 0) a = S[(size_t)(n0 + tid) * N_ANTES + idx_buf[t - 1]];
        a_lds[tid] = a;
    }
    // stage h tile -> h_lds[k][r], spread over all 1024 threads
    #pragma unroll
    for (int i = 0; i < 4; ++i) {
        int r = rq * 4 + i;
        h_lds[jj * HSTR + r] = h[(size_t)(n0 + r) * 256 + jj];
    }

    // 8-deep rotating register prefetch (wpkT padded +8 k-rows)
    float wbuf[8];
    #pragma unroll
    for (int i = 0; i < 8; ++i) wbuf[i] = wpkT[(size_t)i * 1024 + tid];

    const float rs = rowsum[tid];
    const float bs = b_ih[tid] + b_hh[tid];
    __syncthreads();

    float acc[LROWS];
    #pragma unroll
    for (int r = 0; r < LROWS; ++r) acc[r] = fmaf(a_lds[r], rs, bs);

    for (int k8 = 0; k8 < 256; k8 += 8) {
        #pragma unroll
        for (int u = 0; u < 8; ++u) {
            float w = wbuf[u];
            wbuf[u] = wpkT[(size_t)(k8 + 8 + u) * 1024 + tid];  // pad rows ok
            const float4* hrow = (const float4*)&h_lds[(k8 + u) * HSTR];
            float4 h0v = hrow[0], h1v = hrow[1], h2v = hrow[2], h3v = hrow[3];
            float hk[LROWS] = {h0v.x, h0v.y, h0v.z, h0v.w,
                               h1v.x, h1v.y, h1v.z, h1v.w,
                               h2v.x, h2v.y, h2v.z, h2v.w,
                               h3v.x, h3v.y, h3v.z, h3v.w};
            #pragma unroll
            for (int r = 0; r < LROWS; ++r)
                acc[r] = fmaf(w, hk[r], acc[r]);
        }
    }

    // exchange gates, fused c/h update
    #pragma unroll
    for (int r = 0; r < LROWS; ++r) z_lds[r * 1024 + tid] = acc[r];
    __syncthreads();
    float esum = 0.f;
    #pragma unroll
    for (int i = 0; i < 4; ++i) {
        int r = rq * 4 + i;
        float zi = z_lds[r * 1024 + jj];
        float zf = z_lds[r * 1024 + 256 + jj];
        float zg = z_lds[r * 1024 + 512 + jj];
        float zo = z_lds[r * 1024 + 768 + jj];
        size_t off = (size_t)(n0 + r) * 256 + jj;
        float cn = fsig(zf) * c[off] + fsig(zi) * ftanh(zg);
        float hn = fsig(zo) * ftanh(cn);
        c[off] = cn;
        h[off] = hn;
        esum += hn;
    }
    red[tid] = esum;
    __syncthreads();
    if (tid < 256) {
        float e = (red[tid] + red[tid + 256]) + (red[tid + 512] + red[tid + 768]);
        atomicAdd(&e_accum_t[tid], e);
    }
}

// ---------------------------------------------------------------------------
// Fused attention: 32 blocks compute 64 scores each; the last block to finish
// (device-scope counter) does log-softmax + argmax and writes out_t / idx_t.
// ---------------------------------------------------------------------------
__global__ __launch_bounds__(256) void k_att(
    const float* __restrict__ preT, const float* __restrict__ e_accum_t,
    const float* __restrict__ WbT, const float* __restrict__ att_b1,
    const float* __restrict__ att_w2, const float* __restrict__ att_b2,
    float* __restrict__ scores, float* __restrict__ out_t,
    int* __restrict__ idx_t, u32* __restrict__ counter)
{
    __shared__ float e_lds[256];
    __shared__ float u[256];
    __shared__ float w2s[256];
    __shared__ float red[256];
    __shared__ int   ridx[256];
    __shared__ u32 done;
    const int tid = threadIdx.x;

    e_lds[tid] = e_accum_t[tid] * (1.f / (float)N_TRAIN);
    w2s[tid] = att_w2[tid];
    __syncthreads();

    float uacc = att_b1[tid];
    for (int k = 0; k < 256; ++k)
        uacc = fmaf(e_lds[k], WbT[(size_t)k * 256 + tid], uacc);
    u[tid] = uacc;
    __syncthreads();

    const int pl = tid & 63, jq = tid >> 6;
    const int p = blockIdx.x * 64 + pl;
    float sc = 0.f;
    #pragma unroll 4
    for (int j = jq; j < 256; j += 4) {
        float v = preT[(size_t)j * N_ANTES + p] + u[j];
        sc = fmaf(fmaxf(v, 0.f), w2s[j], sc);
    }
    red[tid] = sc;
    __syncthreads();
    if (tid < 64) {
        float s = red[tid] + red[tid + 64] + red[tid + 128] + red[tid + 192]
                + att_b2[0];
        __hip_atomic_store(&scores[blockIdx.x * 64 + tid], s,
                           __ATOMIC_RELAXED, __HIP_MEMORY_SCOPE_AGENT);
    }
    __threadfence();
    __syncthreads();
    if (tid == 0) done = atomicAdd(counter, 1u);
    __syncthreads();
    if (done != 31) return;
    __threadfence();

    // ---- last block: log-softmax + argmax over all 2048 scores ----
    float sv[8];
    #pragma unroll
    for (int i = 0; i < 8; ++i)
        sv[i] = __hip_atomic_load(&scores[tid * 8 + i],
                                  __ATOMIC_RELAXED, __HIP_MEMORY_SCOPE_AGENT);
    float lmax = -INFINITY; int lidx = 0;
    #pragma unroll
    for (int i = 0; i < 8; ++i)
        if (sv[i] > lmax) { lmax = sv[i]; lidx = tid * 8 + i; }
    red[tid] = lmax; ridx[tid] = lidx;
    __syncthreads();
    for (int off = 128; off > 0; off >>= 1) {
        if (tid < off) {
            float ov = red[tid + off]; int oi = ridx[tid + off];
            if (ov > red[tid] || (ov == red[tid] && oi < ridx[tid])) {
                red[tid] = ov; ridx[tid] = oi;
            }
        }
        __syncthreads();
    }
    const float gmax = red[0];
    const int gidx = ridx[0];
    __syncthreads();

    float lsum = 0.f;
    #pragma unroll
    for (int i = 0; i < 8; ++i) lsum += __expf(sv[i] - gmax);
    red[tid] = lsum;
    __syncthreads();
    for (int off = 128; off > 0; off >>= 1) {
        if (tid < off) red[tid] += red[tid + off];
        __syncthreads();
    }
    const float lse = gmax + logf(red[0]);

    #pragma unroll
    for (int i = 0; i < 8; ++i)
        out_t[tid * 8 + i] = sv[i] - lse;
    if (tid == 0) idx_t[0] = gidx;
}

// ---------------------------------------------------------------------------
extern "C" void kernel_launch(void* const* d_in, const int* in_sizes, int n_in,
                              void* d_out, int out_size, void* d_ws, size_t ws_size,
                              hipStream_t stream)
{
    (void)in_sizes; (void)n_in; (void)out_size; (void)ws_size;
    const float* context = (const float*)d_in[0];
    const float* S       = (const float*)d_in[1];
    const float* enc_w1  = (const float*)d_in[2];
    const float* enc_b1  = (const float*)d_in[3];
    const float* enc_w2  = (const float*)d_in[4];
    const float* enc_b2  = (const float*)d_in[5];
    const float* w_ih    = (const float*)d_in[6];
    const float* w_hh    = (const float*)d_in[7];
    const float* b_ih    = (const float*)d_in[8];
    const float* b_hh    = (const float*)d_in[9];
    const float* att_w1  = (const float*)d_in[10];
    const float* att_b1  = (const float*)d_in[11];
    const float* att_w2  = (const float*)d_in[12];
    const float* att_b2  = (const float*)d_in[13];
    float* out = (float*)d_out;
    float* ws  = (float*)d_ws;

    // ws layout (float offsets)
    float* h      = ws;                        // 1,048,576
    float* c      = ws + 1048576;              // 1,048,576
    float* hid1   = ws + 2097152;              // 1,048,576
    float* preT   = ws + 3145728;              // 524,288 (j-major [j][p])
    float* wpkT   = ws + 3670016;              // (256+8)*1024 = 270,336
    float* rowsum = ws + 3940352;              // 1,024
    float* e_acc  = ws + 3941376;              // 4,096
    float* scores = ws + 3945472;              // 2,048
    float* WbT    = ws + 3947520;              // 65,536
    u32*   cnt    = (u32*)(ws + 4013056);      // 16
    int*   idxbuf = (int*)(ws + 4013072);      // 16

    hipMemsetAsync(c, 0, (size_t)N_TRAIN * ENC * sizeof(float), stream);
    hipMemsetAsync(preT, 0, (size_t)ATT_H * N_ANTES * sizeof(float), stream);
    // e_acc (16x256 floats) + 16 counters + 16 idx, contiguous region
    hipMemsetAsync(e_acc, 0, (size_t)MAX_LEN * ENC * sizeof(float), stream);
    hipMemsetAsync(cnt, 0, 32 * sizeof(u32), stream);

    k_rowsum<<<1024, 256, 0, stream>>>(w_ih, rowsum);
    k_packT<<<1024, 256, 0, stream>>>(w_hh, wpkT);
    k_wbT<<<256, 256, 0, stream>>>(att_w1, WbT);

    // encoder: hid1 = relu(context @ enc_w1.T + b1); h = hid1 @ enc_w2.T + b2
    dim3 g1(N_TRAIN / 64, N_HID / 64);
    gemm_abT<true><<<g1, 256, 0, stream>>>(context, enc_w1, enc_b1, hid1,
                                           N_TRAIN, N_HID, N_FEAT, N_FEAT, N_FEAT, N_HID);
    dim3 g2(N_TRAIN / 64, ENC / 64);
    gemm_abT<false><<<g2, 256, 0, stream>>>(hid1, enc_w2, enc_b2, h,
                                            N_TRAIN, ENC, N_HID, N_HID, N_HID, ENC);
    // preT = Wa @ S, split-K=8 atomic accumulate (preT zeroed above)
    dim3 g3(ATT_H / 64, N_ANTES / 64, KSPLIT);
    gemm_ab_splitk<<<g3, 256, 0, stream>>>(att_w1, S, preT,
                                           ATT_H, N_ANTES, N_TRAIN,
                                           N_TRAIN + ENC, N_ANTES, N_ANTES);

    for (int t = 0; t < MAX_LEN; ++t) {
        k_lstm<<<N_TRAIN / LROWS, 1024, 0, stream>>>(h, c, wpkT, rowsum, b_ih,
                                                     b_hh, S, idxbuf, t,
                                                     e_acc + t * 256);
        k_att<<<N_ANTES / 64, 256, 0, stream>>>(preT, e_acc + t * 256, WbT,
                                                att_b1, att_w2, att_b2, scores,
                                                out + t * N_ANTES, idxbuf + t,
                                                cnt + t);
    }
}